// Round 4
// baseline (205.666 us; speedup 1.0000x reference)
//
#include <hip/hip_runtime.h>
#include <stdint.h>

using s16x8 = __attribute__((ext_vector_type(8))) short;
using u16x8 = __attribute__((ext_vector_type(8))) unsigned short;
using f32x4 = __attribute__((ext_vector_type(4))) float;
using u32x2 = __attribute__((ext_vector_type(2))) uint32_t;

__device__ __forceinline__ unsigned short f2bf(float f) {
    union { float f; uint32_t u; } v; v.f = f;
    uint32_t u = (v.u + 0x7FFFu + ((v.u >> 16) & 1u)) >> 16;
    return (unsigned short)u;
}

#if defined(__has_builtin)
#if __has_builtin(__builtin_amdgcn_cvt_pk_bf16_f32)
#define HAS_PK_BF16 1
#endif
#if __has_builtin(__builtin_amdgcn_exp2f)
#define HAS_EXP2 1
#endif
#endif

// raw v_exp_f32: exact in [-126,128]; scores are |s| <~ 20 in log2 domain.
__device__ __forceinline__ float ex2(float x) {
#ifdef HAS_EXP2
    return __builtin_amdgcn_exp2f(x);
#else
    float r; asm("v_exp_f32 %0, %1" : "=v"(r) : "v"(x)); return r;
#endif
}

// pack two fp32 -> two bf16 in a dword (low = x, high = y)
__device__ __forceinline__ uint32_t pk2bf(float x, float y) {
#ifdef HAS_PK_BF16
    typedef __bf16 bf16x2 __attribute__((ext_vector_type(2)));
    union { bf16x2 v; uint32_t u; } c;
    c.v = __builtin_amdgcn_cvt_pk_bf16_f32(x, y);
    return c.u;
#else
    union { __bf16 v[2]; uint32_t u; } c;
    c.v[0] = (__bf16)x; c.v[1] = (__bf16)y;
    return c.u;
#endif
}

__device__ __forceinline__ f32x4 zero4() { f32x4 z = {0.f, 0.f, 0.f, 0.f}; return z; }

// async global->LDS, 16B per lane. LDS dest must be wave-uniform base + lane*16.
__device__ __forceinline__ void async16(const void* g, void* l) {
    __builtin_amdgcn_global_load_lds(
        reinterpret_cast<const uint32_t __attribute__((address_space(1)))*>(
            reinterpret_cast<uintptr_t>(g)),
        reinterpret_cast<uint32_t __attribute__((address_space(3)))*>(
            (uint32_t)reinterpret_cast<uintptr_t>(l)),
        16, 0, 0);
}

#define BARRIER() do { __builtin_amdgcn_s_barrier(); __builtin_amdgcn_sched_barrier(0); } while (0)

// ---------------- fp32 -> bf16 convert (x and W in one launch) ----------------
__global__ void cvt_bf16_2(const float* __restrict__ xa, unsigned short* __restrict__ oa, int na,
                           const float* __restrict__ xb, unsigned short* __restrict__ ob, int nb) {
    int i = (blockIdx.x * 256 + threadIdx.x) * 8;
    const float* in; unsigned short* out;
    if (i < na) { in = xa + i; out = oa + i; }
    else { int k = i - na; if (k >= nb) return; in = xb + k; out = ob + k; }
    f32x4 a = *(const f32x4*)(in);
    f32x4 c = *(const f32x4*)(in + 4);
    u16x8 o;
    o[0] = f2bf(a[0]); o[1] = f2bf(a[1]); o[2] = f2bf(a[2]); o[3] = f2bf(a[3]);
    o[4] = f2bf(c[0]); o[5] = f2bf(c[1]); o[6] = f2bf(c[2]); o[7] = f2bf(c[3]);
    *(u16x8*)(out) = o;
}

#define SC 0.18033688011112042f  // 0.125 * log2(e); folded into Q at GEMM epilogue

// ---------------- QKV GEMM: 256x128 tile, 8 waves, 4-phase counted-vmcnt ----------------
// R11: T3+T4+T5 schedule. 16 K-tiles (BK=64), double-buffered slots (As 2x32KB,
// Bs 2x16KB = 96KB). Per K-tile iter: 4 phases, each {ds_read subtile; stage-issue;
// s_barrier; setprio(1); 8 MFMA; setprio(0); s_barrier}. Staging ledger:
//   A-half h of slot s freed after ph2; B-half g freed after ph1.
//   issues: ph0 -> Ah1(t+1) [2 loads], ph2 -> Bg0(t+2) [1], ph3 -> Bg1(t+2)+Ah0(t+2) [3].
//   vmcnt(4) at ph3-end (keeps tile t+2's 4 loads in flight, drains all of t+1);
//   vmcnt(0) for t>=14 to close the pipe. Loads retire in issue order (vmcnt ISA).
// Grid 24x32 = 768 = 3x256 CUs exactly -> no dispatch tail.
__global__ __launch_bounds__(512, 2)
void qkv_gemm(const unsigned short* __restrict__ A,   // [8192,1024]
              const unsigned short* __restrict__ Bw,  // [3072,1024]
              const float* __restrict__ bias,         // [3072]
              unsigned short* __restrict__ Qo,
              unsigned short* __restrict__ Ko,
              unsigned short* __restrict__ Vto) {     // [64bh][64d][2048t]
    __shared__ __align__(16) unsigned short smem[49152];  // As[2]32KB + Bs[2]16KB; epilogue scratch
    const int tid = threadIdx.x;
    const int wave = tid >> 6, lane = tid & 63;
    const int q4 = lane >> 4, l15 = lane & 15;
    const int bm = blockIdx.y * 256, bn = blockIdx.x * 128;
    const int wrO = (wave >> 2) * 128;   // wave M-origin (2 M-groups)
    const int wcO = (wave & 3) * 32;     // wave N-origin (4 N-groups)

    auto stageA = [&](int t2, int h) {   // A half-tile: 128 rows x 64 k, 2 loads/thread
#pragma unroll
        for (int r = 0; r < 2; ++r) {
            int w = r * 512 + tid, row = w >> 3, su = (w & 7) ^ (row & 7);
            async16(A + (size_t)(bm + h * 128 + row) * 1024 + t2 * 64 + su * 8,
                    (char*)(smem + (t2 & 1) * 16384 + h * 8192) + w * 16);
        }
    };
    auto stageB = [&](int t2, int g) {   // B half-tile: 64 rows x 64 k, 1 load/thread
        int w = tid, row = w >> 3, su = (w & 7) ^ (row & 7);
        async16(Bw + (size_t)(bn + g * 64 + row) * 1024 + t2 * 64 + su * 8,
                (char*)(smem + 32768 + (t2 & 1) * 8192 + g * 4096) + w * 16);
    };

    f32x4 acc[8][2];
#pragma unroll
    for (int a = 0; a < 8; ++a) { acc[a][0] = zero4(); acc[a][1] = zero4(); }

    // prologue: tiles 0 and 1 fully staged, drained
#pragma unroll
    for (int t2 = 0; t2 < 2; ++t2) {
        stageA(t2, 0); stageA(t2, 1);
        stageB(t2, 0); stageB(t2, 1);
    }
    asm volatile("s_waitcnt vmcnt(0)" ::: "memory");
    __syncthreads();

#pragma unroll 2
    for (int t = 0; t < 16; ++t) {
        const unsigned short* As_s = smem + (t & 1) * 16384;
        const unsigned short* Bs_s = smem + 32768 + (t & 1) * 8192;
        s16x8 af[4][2], bf[2][2];
        // ---- ph0: read A(mf0-3) + B(nf0); stage Ah1(t+1); MFMA Q(m0,n0) ----
#pragma unroll
        for (int mf = 0; mf < 4; ++mf) {
            const unsigned short* p = As_s + (wrO + mf * 16 + l15) * 64;
#pragma unroll
            for (int kt = 0; kt < 2; ++kt)
                af[mf][kt] = *(const s16x8*)(p + (((kt * 4 + q4) ^ (l15 & 7)) << 3));
        }
        {
            const unsigned short* p = Bs_s + (wcO + l15) * 64;
#pragma unroll
            for (int kt = 0; kt < 2; ++kt)
                bf[0][kt] = *(const s16x8*)(p + (((kt * 4 + q4) ^ (l15 & 7)) << 3));
        }
        if (t >= 1 && t <= 14) stageA(t + 1, 1);
        BARRIER();
        __builtin_amdgcn_s_setprio(1);
#pragma unroll
        for (int kt = 0; kt < 2; ++kt)
#pragma unroll
            for (int mf = 0; mf < 4; ++mf)
                acc[mf][0] = __builtin_amdgcn_mfma_f32_16x16x32_bf16(af[mf][kt], bf[0][kt], acc[mf][0], 0, 0, 0);
        __builtin_amdgcn_s_setprio(0);
        BARRIER();
        // ---- ph1: read B(nf1); MFMA Q(m0,n1) ----
        {
            const unsigned short* p = Bs_s + (wcO + 16 + l15) * 64;
#pragma unroll
            for (int kt = 0; kt < 2; ++kt)
                bf[1][kt] = *(const s16x8*)(p + (((kt * 4 + q4) ^ (l15 & 7)) << 3));
        }
        BARRIER();
        __builtin_amdgcn_s_setprio(1);
#pragma unroll
        for (int kt = 0; kt < 2; ++kt)
#pragma unroll
            for (int mf = 0; mf < 4; ++mf)
                acc[mf][1] = __builtin_amdgcn_mfma_f32_16x16x32_bf16(af[mf][kt], bf[1][kt], acc[mf][1], 0, 0, 0);
        __builtin_amdgcn_s_setprio(0);
        BARRIER();
        // ---- ph2: read A(mf4-7); stage Bg0(t+2); MFMA Q(m1,n1) ----
#pragma unroll
        for (int mf = 0; mf < 4; ++mf) {
            const unsigned short* p = As_s + (wrO + 64 + mf * 16 + l15) * 64;
#pragma unroll
            for (int kt = 0; kt < 2; ++kt)
                af[mf][kt] = *(const s16x8*)(p + (((kt * 4 + q4) ^ (l15 & 7)) << 3));
        }
        if (t <= 13) stageB(t + 2, 0);
        BARRIER();
        __builtin_amdgcn_s_setprio(1);
#pragma unroll
        for (int kt = 0; kt < 2; ++kt)
#pragma unroll
            for (int mf = 0; mf < 4; ++mf)
                acc[4 + mf][1] = __builtin_amdgcn_mfma_f32_16x16x32_bf16(af[mf][kt], bf[1][kt], acc[4 + mf][1], 0, 0, 0);
        __builtin_amdgcn_s_setprio(0);
        BARRIER();
        // ---- ph3: stage Bg1(t+2)+Ah0(t+2); MFMA Q(m1,n0); counted vmcnt ----
        if (t <= 13) { stageB(t + 2, 1); stageA(t + 2, 0); }
        BARRIER();
        __builtin_amdgcn_s_setprio(1);
#pragma unroll
        for (int kt = 0; kt < 2; ++kt)
#pragma unroll
            for (int mf = 0; mf < 4; ++mf)
                acc[4 + mf][0] = __builtin_amdgcn_mfma_f32_16x16x32_bf16(af[mf][kt], bf[0][kt], acc[4 + mf][0], 0, 0, 0);
        __builtin_amdgcn_s_setprio(0);
        if (t < 14) { asm volatile("s_waitcnt vmcnt(4)" ::: "memory"); }
        else        { asm volatile("s_waitcnt vmcnt(0)" ::: "memory"); }
        BARRIER();
    }
    __syncthreads();

    if (bn >= 2048) {
        // V: acc -> scratch [d_local 128][m_local 256], stride 264 (+8 pad: 2-way max)
#pragma unroll
        for (int nf = 0; nf < 2; ++nf) {
            int n = bn + wcO + nf * 16 + l15;
            float bv = bias[n];
            int dl = wcO + nf * 16 + l15;
#pragma unroll
            for (int mf = 0; mf < 8; ++mf)
#pragma unroll
                for (int i = 0; i < 4; ++i) {
                    int ml = wrO + mf * 16 + 4 * q4 + i;
                    smem[dl * 264 + ml] = f2bf(acc[mf][nf][i] + bv);
                }
        }
        __syncthreads();
        const int bb = bm >> 11, t0 = bm & 2047;
#pragma unroll
        for (int rr = 0; rr < 4; ++rr) {
            int r = wave * 16 + rr * 4 + q4;      // d_local 0..127
            int d = (bn - 2048) + r;
            int h = d >> 6, dd = d & 63;
#pragma unroll
            for (int seg = 0; seg < 2; ++seg) {
                u16x8 v = *(const u16x8*)(smem + r * 264 + seg * 128 + l15 * 8);
                *(u16x8*)(Vto + (((size_t)(bb * 16 + h)) * 64 + dd) * 2048 + t0 + seg * 128 + l15 * 8) = v;
            }
        }
    } else {
#pragma unroll
        for (int nf = 0; nf < 2; ++nf) {
            int n = bn + wcO + nf * 16 + l15;
            float bv = bias[n];
            int which = n >> 10, h = (n >> 6) & 15, d = n & 63;
            unsigned short* dst = (which == 0) ? Qo : Ko;
            float scl = (which == 0) ? SC : 1.0f;
#pragma unroll
            for (int mf = 0; mf < 8; ++mf)
#pragma unroll
                for (int i = 0; i < 4; ++i) {
                    int m = bm + wrO + mf * 16 + 4 * q4 + i;
                    int bb = m >> 11, tt = m & 2047;
                    dst[((((size_t)bb * 16 + h) * 2048) + tt) * 64 + d] = f2bf((acc[mf][nf][i] + bv) * scl);
                }
        }
    }
}

// ---------------- flash attention (R1 version, 56.0 us measured) ----------------
__global__ __launch_bounds__(256, 3)
void flash_attn(const unsigned short* __restrict__ Qg,
                const unsigned short* __restrict__ Kg,
                const unsigned short* __restrict__ Vtg,
                float* __restrict__ Out) {
    constexpr int T = 2048;
    __shared__ __align__(16) unsigned short Qs[128 * 64];     // Q tile; then P strips
    __shared__ __align__(16) unsigned short Ks[2][64 * 64];   // swizzled, dbuf
    __shared__ __align__(16) unsigned short Vt[2][64 * 64];   // V^T, swizzled, dbuf

    const int tid = threadIdx.x;
    const int wave = tid >> 6, lane = tid & 63;
    const int q4 = lane >> 4, l15 = lane & 15;
    const int bh = blockIdx.x;
    const int qt = (int)gridDim.y - 1 - (int)blockIdx.y;  // heavy blocks first
    const int b = bh >> 4, h = bh & 15;
    const int q0 = qt * 128;
    const unsigned short* qb = Qg + (size_t)bh * T * 64;
    const unsigned short* kb = Kg + (size_t)bh * T * 64;
    const unsigned short* vtb = Vtg + (size_t)bh * 64 * T;  // [d][t]

    // stage Q (128 rows) + prefetch kv-tile 0 into buf 0
#pragma unroll
    for (int r = 0; r < 4; ++r) {
        int u = r * 256 + tid;
        int row = u >> 3, su = (u & 7) ^ (row & 7);
        async16(qb + (size_t)(q0 + row) * 64 + su * 8, (char*)Qs + u * 16);
    }
#pragma unroll
    for (int r = 0; r < 2; ++r) {
        int u = r * 256 + tid;
        int row = u >> 3, su = (u & 7) ^ (row & 7);
        async16(kb + (size_t)row * 64 + su * 8, (char*)Ks[0] + u * 16);
        async16(vtb + (size_t)row * T + su * 8, (char*)Vt[0] + u * 16);
    }
    __syncthreads();  // Q + tile0 ready
    s16x8 aq[2][2];
#pragma unroll
    for (int s = 0; s < 2; ++s)
#pragma unroll
        for (int kt = 0; kt < 2; ++kt) {
            int arow = s * 64 + wave * 16 + l15;
            int au = (kt * 4 + q4) ^ (arow & 7);
            aq[s][kt] = *(const s16x8*)(Qs + arow * 64 + au * 8);
        }
    __syncthreads();  // all waves' hoists done before any P store overwrites Qs
    unsigned short* const Ps0 = Qs + (wave * 2 + 0) * 1024;  // 16x64, swizzled units
    unsigned short* const Ps1 = Qs + (wave * 2 + 1) * 1024;

    f32x4 oacc[2][4];
    float lsum[2] = {0.f, 0.f};
#pragma unroll
    for (int s = 0; s < 2; ++s)
#pragma unroll
        for (int ct = 0; ct < 4; ++ct) oacc[s][ct] = zero4();

    const int nkt = 2 * qt + 2;  // always even

    auto tile_step = [&](int j,
                         const unsigned short* __restrict__ kcur,
                         const unsigned short* __restrict__ vcur,
                         unsigned short* __restrict__ kd,
                         unsigned short* __restrict__ vd) {
        if (j + 1 < nkt) {
            const int cn = (j + 1) * 64;
#pragma unroll
            for (int r = 0; r < 2; ++r) {
                int u = r * 256 + tid;
                int row = u >> 3, su = (u & 7) ^ (row & 7);
                async16(kb + (size_t)(cn + row) * 64 + su * 8, (char*)kd + u * 16);
                async16(vtb + (size_t)row * T + cn + su * 8, (char*)vd + u * 16);
            }
        }
        const int c0 = j * 64;
        const bool alive0 = (j <= 2 * qt);

        f32x4 sv[2][4];
#pragma unroll
        for (int s = 0; s < 2; ++s)
#pragma unroll
            for (int t = 0; t < 4; ++t) sv[s][t] = zero4();
#pragma unroll
        for (int kt = 0; kt < 2; ++kt) {
#pragma unroll
            for (int t = 0; t < 4; ++t) {
                int krow = t * 16 + l15;
                int ku = (kt * 4 + q4) ^ (krow & 7);
                s16x8 ak = *(const s16x8*)(kcur + krow * 64 + ku * 8);
                sv[0][t] = __builtin_amdgcn_mfma_f32_16x16x32_bf16(ak, aq[0][kt], sv[0][t], 0, 0, 0);
                sv[1][t] = __builtin_amdgcn_mfma_f32_16x16x32_bf16(ak, aq[1][kt], sv[1][t], 0, 0, 0);
            }
        }

#pragma unroll
        for (int s = 0; s < 2; ++s) {
            if (s == 0 && !alive0) continue;  // wave-uniform
            const bool dg = (j == 2 * qt + s);
            unsigned short* const ps = (s == 0) ? Ps0 : Ps1;
            const int qrow = q0 + s * 64 + wave * 16 + l15;
#pragma unroll
            for (int t = 0; t < 4; ++t) {
                float p0 = ex2(sv[s][t][0]);
                float p1 = ex2(sv[s][t][1]);
                float p2 = ex2(sv[s][t][2]);
                float p3 = ex2(sv[s][t][3]);
                if (dg) {
                    int col = c0 + t * 16 + 4 * q4;
                    if (col + 0 > qrow) p0 = 0.f;
                    if (col + 1 > qrow) p1 = 0.f;
                    if (col + 2 > qrow) p2 = 0.f;
                    if (col + 3 > qrow) p3 = 0.f;
                }
                lsum[s] += (p0 + p1) + (p2 + p3);
                u32x2 w;
                w[0] = pk2bf(p0, p1);
                w[1] = pk2bf(p2, p3);
                *(u32x2*)(ps + l15 * 64 + (((2 * t + (q4 >> 1)) ^ (l15 & 7)) << 3) +
                          ((q4 & 1) << 2)) = w;
            }
        }

#pragma unroll
        for (int kt = 0; kt < 2; ++kt) {
            int pu = ((kt * 4 + q4) ^ (l15 & 7)) * 8;
            s16x8 pa0, pa1;
            if (alive0) pa0 = *(const s16x8*)(Ps0 + l15 * 64 + pu);
            pa1 = *(const s16x8*)(Ps1 + l15 * 64 + pu);
#pragma unroll
            for (int ct = 0; ct < 4; ++ct) {
                int vrow = ct * 16 + l15;
                int vu = (kt * 4 + q4) ^ (vrow & 7);
                s16x8 vv = *(const s16x8*)(vcur + vrow * 64 + vu * 8);
                if (alive0)
                    oacc[0][ct] = __builtin_amdgcn_mfma_f32_16x16x32_bf16(pa0, vv, oacc[0][ct], 0, 0, 0);
                oacc[1][ct] = __builtin_amdgcn_mfma_f32_16x16x32_bf16(pa1, vv, oacc[1][ct], 0, 0, 0);
            }
        }
        __syncthreads();
    };

    for (int j = 0; j < nkt; j += 2) {
        tile_step(j + 0, Ks[0], Vt[0], Ks[1], Vt[1]);
        tile_step(j + 1, Ks[1], Vt[1], Ks[0], Vt[0]);
    }

#pragma unroll
    for (int s = 0; s < 2; ++s) {
        float rs = lsum[s];
        rs += __shfl_xor(rs, 16, 64);
        rs += __shfl_xor(rs, 32, 64);
        float inv[4];
#pragma unroll
        for (int i = 0; i < 4; ++i)
            inv[i] = 1.0f / __shfl(rs, 4 * q4 + i, 64);
#pragma unroll
        for (int ct = 0; ct < 4; ++ct)
#pragma unroll
            for (int i = 0; i < 4; ++i) {
                int row = q0 + s * 64 + wave * 16 + 4 * q4 + i;
                Out[((size_t)b * T + row) * 1024 + h * 64 + ct * 16 + l15] =
                    oacc[s][ct][i] * inv[i];
            }
    }
}

extern "C" void kernel_launch(void* const* d_in, const int* in_sizes, int n_in,
                              void* d_out, int out_size, void* d_ws, size_t ws_size,
                              hipStream_t stream) {
    const float* x = (const float*)d_in[0];     // [4,2048,1024]
    const float* W = (const float*)d_in[1];     // [3072,1024]
    const float* bias = (const float*)d_in[2];  // [3072]
    float* out = (float*)d_out;                 // [4,2048,1024]

    unsigned short* xb = (unsigned short*)d_ws;      // 8388608
    unsigned short* wb = xb + 8388608;               // 3145728
    unsigned short* qb = wb + 3145728;               // 8388608 each
    unsigned short* kb = qb + 8388608;
    unsigned short* vtb = kb + 8388608;              // V^T [bh][d][t]

    cvt_bf16_2<<<dim3((8388608 + 3145728) / 2048), dim3(256), 0, stream>>>(
        x, xb, 8388608, W, wb, 3145728);
    qkv_gemm<<<dim3(24, 32), dim3(512), 0, stream>>>(xb, wb, bias, qb, kb, vtb);
    flash_attn<<<dim3(64, 16), dim3(256), 0, stream>>>(qb, kb, vtb, out);
}

// Round 5
// 202.269 us; speedup vs baseline: 1.0168x; 1.0168x over previous
//
#include <hip/hip_runtime.h>
#include <stdint.h>

using s16x8 = __attribute__((ext_vector_type(8))) short;
using u16x8 = __attribute__((ext_vector_type(8))) unsigned short;
using f32x4 = __attribute__((ext_vector_type(4))) float;
using u32x2 = __attribute__((ext_vector_type(2))) uint32_t;

__device__ __forceinline__ unsigned short f2bf(float f) {
    union { float f; uint32_t u; } v; v.f = f;
    uint32_t u = (v.u + 0x7FFFu + ((v.u >> 16) & 1u)) >> 16;
    return (unsigned short)u;
}

#if defined(__has_builtin)
#if __has_builtin(__builtin_amdgcn_cvt_pk_bf16_f32)
#define HAS_PK_BF16 1
#endif
#if __has_builtin(__builtin_amdgcn_exp2f)
#define HAS_EXP2 1
#endif
#endif

// raw v_exp_f32: exact in [-126,128]; scores are |s| <~ 20 in log2 domain.
__device__ __forceinline__ float ex2(float x) {
#ifdef HAS_EXP2
    return __builtin_amdgcn_exp2f(x);
#else
    float r; asm("v_exp_f32 %0, %1" : "=v"(r) : "v"(x)); return r;
#endif
}

// pack two fp32 -> two bf16 in a dword (low = x, high = y)
__device__ __forceinline__ uint32_t pk2bf(float x, float y) {
#ifdef HAS_PK_BF16
    typedef __bf16 bf16x2 __attribute__((ext_vector_type(2)));
    union { bf16x2 v; uint32_t u; } c;
    c.v = __builtin_amdgcn_cvt_pk_bf16_f32(x, y);
    return c.u;
#else
    union { __bf16 v[2]; uint32_t u; } c;
    c.v[0] = (__bf16)x; c.v[1] = (__bf16)y;
    return c.u;
#endif
}

__device__ __forceinline__ f32x4 zero4() { f32x4 z = {0.f, 0.f, 0.f, 0.f}; return z; }

// async global->LDS, 16B per lane. LDS dest must be wave-uniform base + lane*16.
__device__ __forceinline__ void async16(const void* g, void* l) {
    __builtin_amdgcn_global_load_lds(
        reinterpret_cast<const uint32_t __attribute__((address_space(1)))*>(
            reinterpret_cast<uintptr_t>(g)),
        reinterpret_cast<uint32_t __attribute__((address_space(3)))*>(
            (uint32_t)reinterpret_cast<uintptr_t>(l)),
        16, 0, 0);
}

// ---------------- fp32 -> bf16 convert (x and W in one launch) ----------------
__global__ void cvt_bf16_2(const float* __restrict__ xa, unsigned short* __restrict__ oa, int na,
                           const float* __restrict__ xb, unsigned short* __restrict__ ob, int nb) {
    int i = (blockIdx.x * 256 + threadIdx.x) * 8;
    const float* in; unsigned short* out;
    if (i < na) { in = xa + i; out = oa + i; }
    else { int k = i - na; if (k >= nb) return; in = xb + k; out = ob + k; }
    f32x4 a = *(const f32x4*)(in);
    f32x4 c = *(const f32x4*)(in + 4);
    u16x8 o;
    o[0] = f2bf(a[0]); o[1] = f2bf(a[1]); o[2] = f2bf(a[2]); o[3] = f2bf(a[3]);
    o[4] = f2bf(c[0]); o[5] = f2bf(c[1]); o[6] = f2bf(c[2]); o[7] = f2bf(c[3]);
    *(u16x8*)(out) = o;
}

#define SC 0.18033688011112042f  // 0.125 * log2(e); folded into Q at GEMM epilogue

// ---------------- QKV GEMM ----------------
// R12: R1's proven 128x128 structure + minimum-2-phase double-buffer (T3-min):
//   for t: { stage(t+1) -> slot^1; ds_read+MFMA from slot; __syncthreads }
// Every DMA now has a full compute phase (~350 cyc) in flight before the
// end-of-iter vmcnt(0) drain (R1 staged the CURRENT tile and drained at once),
// and there is ONE barrier per K-tile instead of two.
// Hazards: stage(t+1) writes slot^1, whose iter-(t-1) reads finished before the
// previous __syncthreads (full lgkm+vm drain); slot-t reads vs slot^1 DMA writes
// are disjoint. V-epilogue scratch (34KB) reuses the 64KB staging area after
// the loop's final barrier.
__global__ __launch_bounds__(256, 2)
void qkv_gemm(const unsigned short* __restrict__ A,   // [8192,1024]
              const unsigned short* __restrict__ Bw,  // [3072,1024]
              const float* __restrict__ bias,         // [3072]
              unsigned short* __restrict__ Qo,
              unsigned short* __restrict__ Ko,
              unsigned short* __restrict__ Vto) {     // [64bh][64d][2048t]
    constexpr int Kd = 1024, T = 2048, H = 16;
    __shared__ __align__(16) unsigned short smem[2][16384];  // per slot: As 8192 | Bs 8192
    const int tid = threadIdx.x;
    const int wave = tid >> 6, lane = tid & 63;
    const int q4 = lane >> 4, l15 = lane & 15;
    const int bm = blockIdx.y * 128, bn = blockIdx.x * 128;
    const int wm = (wave >> 1) * 64, wn = (wave & 1) * 64;

    auto stage = [&](int t) {  // stage K-tile t into slot t&1
        const int k0 = t * 64;
        unsigned short* As = smem[t & 1];
        unsigned short* Bs = smem[t & 1] + 8192;
#pragma unroll
        for (int r = 0; r < 4; ++r) {
            int u = r * 256 + tid;
            int row = u >> 3, su = (u & 7) ^ (row & 7);
            async16(A + (size_t)(bm + row) * Kd + k0 + su * 8, (char*)As + u * 16);
        }
#pragma unroll
        for (int r = 0; r < 4; ++r) {
            int u = r * 256 + tid;
            int row = u >> 3, su = (u & 7) ^ (row & 7);
            async16(Bw + (size_t)(bn + row) * Kd + k0 + su * 8, (char*)Bs + u * 16);
        }
    };

    f32x4 acc[4][4];
#pragma unroll
    for (int a = 0; a < 4; ++a)
#pragma unroll
        for (int c = 0; c < 4; ++c) acc[a][c] = zero4();

    stage(0);
    __syncthreads();  // tile 0 resident

#pragma unroll 2
    for (int t = 0; t < 16; ++t) {
        if (t < 15) stage(t + 1);  // in flight during compute of t
        const unsigned short* As = smem[t & 1];
        const unsigned short* Bs = smem[t & 1] + 8192;
#pragma unroll
        for (int kt = 0; kt < 2; ++kt) {
            s16x8 af[4];
#pragma unroll
            for (int mt = 0; mt < 4; ++mt) {
                int row = wm + mt * 16 + l15;
                int uu = (kt * 4 + q4) ^ (row & 7);
                af[mt] = *(const s16x8*)(As + row * 64 + uu * 8);
            }
#pragma unroll
            for (int nt = 0; nt < 4; ++nt) {
                int row = wn + nt * 16 + l15;
                int uu = (kt * 4 + q4) ^ (row & 7);
                s16x8 bfv = *(const s16x8*)(Bs + row * 64 + uu * 8);
#pragma unroll
                for (int mt = 0; mt < 4; ++mt)
                    acc[mt][nt] = __builtin_amdgcn_mfma_f32_16x16x32_bf16(af[mt], bfv, acc[mt][nt], 0, 0, 0);
            }
        }
        __syncthreads();  // waits tile t+1 DMA (compute of t was in flight) + frees slot t&1
    }

    unsigned short* const scr = &smem[0][0];  // 32768 shorts >= 17408 needed
    if (bn >= 2048) {
        // V: C-tile -> scratch [d_local][m_local] (stride 136), then coalesced V^T rows
#pragma unroll
        for (int nt = 0; nt < 4; ++nt) {
            int n = bn + wn + nt * 16 + l15;
            float bv = bias[n];
            int dl = wn + nt * 16 + l15;
#pragma unroll
            for (int mt = 0; mt < 4; ++mt)
#pragma unroll
                for (int i = 0; i < 4; ++i) {
                    int ml = wm + mt * 16 + 4 * q4 + i;
                    scr[dl * 136 + ml] = f2bf(acc[mt][nt][i] + bv);
                }
        }
        __syncthreads();
        const int bb = bm >> 11, t0 = bm & (T - 1);
#pragma unroll
        for (int rr = 0; rr < 8; ++rr) {
            int r = wave * 32 + rr * 4 + q4;      // d_local
            int d = (bn - 2048) + r;              // 0..1023
            int h = d >> 6, dd = d & 63;
            u16x8 v = *(const u16x8*)(scr + r * 136 + l15 * 8);
            *(u16x8*)(Vto + (((size_t)(bb * H + h)) * 64 + dd) * T + t0 + l15 * 8) = v;
        }
    } else {
#pragma unroll
        for (int nt = 0; nt < 4; ++nt) {
            int n = bn + wn + nt * 16 + l15;
            float bv = bias[n];
            int which = n >> 10, h = (n >> 6) & (H - 1), d = n & 63;
            unsigned short* dst = (which == 0) ? Qo : Ko;
            float scl = (which == 0) ? SC : 1.0f;
#pragma unroll
            for (int mt = 0; mt < 4; ++mt)
#pragma unroll
                for (int i = 0; i < 4; ++i) {
                    int m = bm + wm + mt * 16 + 4 * q4 + i;
                    int bb = m >> 11, tt = m & (T - 1);
                    dst[((((size_t)bb * H + h) * T) + tt) * 64 + d] = f2bf((acc[mt][nt][i] + bv) * scl);
                }
        }
    }
}

// ---------------- flash attention (R1 version, 56.0 us measured) ----------------
__global__ __launch_bounds__(256, 3)
void flash_attn(const unsigned short* __restrict__ Qg,
                const unsigned short* __restrict__ Kg,
                const unsigned short* __restrict__ Vtg,
                float* __restrict__ Out) {
    constexpr int T = 2048;
    __shared__ __align__(16) unsigned short Qs[128 * 64];     // Q tile; then P strips
    __shared__ __align__(16) unsigned short Ks[2][64 * 64];   // swizzled, dbuf
    __shared__ __align__(16) unsigned short Vt[2][64 * 64];   // V^T, swizzled, dbuf

    const int tid = threadIdx.x;
    const int wave = tid >> 6, lane = tid & 63;
    const int q4 = lane >> 4, l15 = lane & 15;
    const int bh = blockIdx.x;
    const int qt = (int)gridDim.y - 1 - (int)blockIdx.y;  // heavy blocks first
    const int b = bh >> 4, h = bh & 15;
    const int q0 = qt * 128;
    const unsigned short* qb = Qg + (size_t)bh * T * 64;
    const unsigned short* kb = Kg + (size_t)bh * T * 64;
    const unsigned short* vtb = Vtg + (size_t)bh * 64 * T;  // [d][t]

    // stage Q (128 rows) + prefetch kv-tile 0 into buf 0
#pragma unroll
    for (int r = 0; r < 4; ++r) {
        int u = r * 256 + tid;
        int row = u >> 3, su = (u & 7) ^ (row & 7);
        async16(qb + (size_t)(q0 + row) * 64 + su * 8, (char*)Qs + u * 16);
    }
#pragma unroll
    for (int r = 0; r < 2; ++r) {
        int u = r * 256 + tid;
        int row = u >> 3, su = (u & 7) ^ (row & 7);
        async16(kb + (size_t)row * 64 + su * 8, (char*)Ks[0] + u * 16);
        async16(vtb + (size_t)row * T + su * 8, (char*)Vt[0] + u * 16);
    }
    __syncthreads();  // Q + tile0 ready
    s16x8 aq[2][2];
#pragma unroll
    for (int s = 0; s < 2; ++s)
#pragma unroll
        for (int kt = 0; kt < 2; ++kt) {
            int arow = s * 64 + wave * 16 + l15;
            int au = (kt * 4 + q4) ^ (arow & 7);
            aq[s][kt] = *(const s16x8*)(Qs + arow * 64 + au * 8);
        }
    __syncthreads();  // all waves' hoists done before any P store overwrites Qs
    unsigned short* const Ps0 = Qs + (wave * 2 + 0) * 1024;  // 16x64, swizzled units
    unsigned short* const Ps1 = Qs + (wave * 2 + 1) * 1024;

    f32x4 oacc[2][4];
    float lsum[2] = {0.f, 0.f};
#pragma unroll
    for (int s = 0; s < 2; ++s)
#pragma unroll
        for (int ct = 0; ct < 4; ++ct) oacc[s][ct] = zero4();

    const int nkt = 2 * qt + 2;  // always even

    auto tile_step = [&](int j,
                         const unsigned short* __restrict__ kcur,
                         const unsigned short* __restrict__ vcur,
                         unsigned short* __restrict__ kd,
                         unsigned short* __restrict__ vd) {
        if (j + 1 < nkt) {
            const int cn = (j + 1) * 64;
#pragma unroll
            for (int r = 0; r < 2; ++r) {
                int u = r * 256 + tid;
                int row = u >> 3, su = (u & 7) ^ (row & 7);
                async16(kb + (size_t)(cn + row) * 64 + su * 8, (char*)kd + u * 16);
                async16(vtb + (size_t)row * T + cn + su * 8, (char*)vd + u * 16);
            }
        }
        const int c0 = j * 64;
        const bool alive0 = (j <= 2 * qt);

        f32x4 sv[2][4];
#pragma unroll
        for (int s = 0; s < 2; ++s)
#pragma unroll
            for (int t = 0; t < 4; ++t) sv[s][t] = zero4();
#pragma unroll
        for (int kt = 0; kt < 2; ++kt) {
#pragma unroll
            for (int t = 0; t < 4; ++t) {
                int krow = t * 16 + l15;
                int ku = (kt * 4 + q4) ^ (krow & 7);
                s16x8 ak = *(const s16x8*)(kcur + krow * 64 + ku * 8);
                sv[0][t] = __builtin_amdgcn_mfma_f32_16x16x32_bf16(ak, aq[0][kt], sv[0][t], 0, 0, 0);
                sv[1][t] = __builtin_amdgcn_mfma_f32_16x16x32_bf16(ak, aq[1][kt], sv[1][t], 0, 0, 0);
            }
        }

#pragma unroll
        for (int s = 0; s < 2; ++s) {
            if (s == 0 && !alive0) continue;  // wave-uniform
            const bool dg = (j == 2 * qt + s);
            unsigned short* const ps = (s == 0) ? Ps0 : Ps1;
            const int qrow = q0 + s * 64 + wave * 16 + l15;
#pragma unroll
            for (int t = 0; t < 4; ++t) {
                float p0 = ex2(sv[s][t][0]);
                float p1 = ex2(sv[s][t][1]);
                float p2 = ex2(sv[s][t][2]);
                float p3 = ex2(sv[s][t][3]);
                if (dg) {
                    int col = c0 + t * 16 + 4 * q4;
                    if (col + 0 > qrow) p0 = 0.f;
                    if (col + 1 > qrow) p1 = 0.f;
                    if (col + 2 > qrow) p2 = 0.f;
                    if (col + 3 > qrow) p3 = 0.f;
                }
                lsum[s] += (p0 + p1) + (p2 + p3);
                u32x2 w;
                w[0] = pk2bf(p0, p1);
                w[1] = pk2bf(p2, p3);
                *(u32x2*)(ps + l15 * 64 + (((2 * t + (q4 >> 1)) ^ (l15 & 7)) << 3) +
                          ((q4 & 1) << 2)) = w;
            }
        }

#pragma unroll
        for (int kt = 0; kt < 2; ++kt) {
            int pu = ((kt * 4 + q4) ^ (l15 & 7)) * 8;
            s16x8 pa0, pa1;
            if (alive0) pa0 = *(const s16x8*)(Ps0 + l15 * 64 + pu);
            pa1 = *(const s16x8*)(Ps1 + l15 * 64 + pu);
#pragma unroll
            for (int ct = 0; ct < 4; ++ct) {
                int vrow = ct * 16 + l15;
                int vu = (kt * 4 + q4) ^ (vrow & 7);
                s16x8 vv = *(const s16x8*)(vcur + vrow * 64 + vu * 8);
                if (alive0)
                    oacc[0][ct] = __builtin_amdgcn_mfma_f32_16x16x32_bf16(pa0, vv, oacc[0][ct], 0, 0, 0);
                oacc[1][ct] = __builtin_amdgcn_mfma_f32_16x16x32_bf16(pa1, vv, oacc[1][ct], 0, 0, 0);
            }
        }
        __syncthreads();
    };

    for (int j = 0; j < nkt; j += 2) {
        tile_step(j + 0, Ks[0], Vt[0], Ks[1], Vt[1]);
        tile_step(j + 1, Ks[1], Vt[1], Ks[0], Vt[0]);
    }

#pragma unroll
    for (int s = 0; s < 2; ++s) {
        float rs = lsum[s];
        rs += __shfl_xor(rs, 16, 64);
        rs += __shfl_xor(rs, 32, 64);
        float inv[4];
#pragma unroll
        for (int i = 0; i < 4; ++i)
            inv[i] = 1.0f / __shfl(rs, 4 * q4 + i, 64);
#pragma unroll
        for (int ct = 0; ct < 4; ++ct)
#pragma unroll
            for (int i = 0; i < 4; ++i) {
                int row = q0 + s * 64 + wave * 16 + 4 * q4 + i;
                Out[((size_t)b * T + row) * 1024 + h * 64 + ct * 16 + l15] =
                    oacc[s][ct][i] * inv[i];
            }
    }
}

extern "C" void kernel_launch(void* const* d_in, const int* in_sizes, int n_in,
                              void* d_out, int out_size, void* d_ws, size_t ws_size,
                              hipStream_t stream) {
    const float* x = (const float*)d_in[0];     // [4,2048,1024]
    const float* W = (const float*)d_in[1];     // [3072,1024]
    const float* bias = (const float*)d_in[2];  // [3072]
    float* out = (float*)d_out;                 // [4,2048,1024]

    unsigned short* xb = (unsigned short*)d_ws;      // 8388608
    unsigned short* wb = xb + 8388608;               // 3145728
    unsigned short* qb = wb + 3145728;               // 8388608 each
    unsigned short* kb = qb + 8388608;
    unsigned short* vtb = kb + 8388608;              // V^T [bh][d][t]

    cvt_bf16_2<<<dim3((8388608 + 3145728) / 2048), dim3(256), 0, stream>>>(
        x, xb, 8388608, W, wb, 3145728);
    qkv_gemm<<<dim3(24, 64), dim3(256), 0, stream>>>(xb, wb, bias, qb, kb, vtb);
    flash_attn<<<dim3(64, 16), dim3(256), 0, stream>>>(qb, kb, vtb, out);
}